// Round 14
// baseline (648.163 us; speedup 1.0000x reference)
//
#include <hip/hip_runtime.h>
#include <hip/hip_cooperative_groups.h>
#include <cstdint>

namespace cg = cooperative_groups;

#define B_ 2
#define N_ 50000
#define D_ 128
#define E_ 800000
#define TOK 100000   // B_*N_

typedef __bf16 bf16x8 __attribute__((ext_vector_type(8)));
typedef float f32x4 __attribute__((ext_vector_type(4)));

__device__ __forceinline__ unsigned short f2bf(float f) {
  union { float f; uint32_t u; } v; v.f = f;
  uint32_t u = v.u;
  return (unsigned short)((u + 0x7FFFu + ((u >> 16) & 1u)) >> 16);
}
__device__ __forceinline__ float uasf(uint32_t u) {
  union { uint32_t u; float f; } v; v.u = u; return v.f;
}
// tanh-form GELU: v * sigmoid(1.5958*(v + 0.044715 v^3)); max |err| vs exact
// erf-GELU ~3e-4 << bf16 rounding of h1. Branch-free saturation.
__device__ __forceinline__ float fast_gelu(float v) {
  float p = v * (1.5957691f + 0.07135481f * v * v);
  return v * __builtin_amdgcn_rcpf(1.0f + __expf(-p));
}

// ======= cooperative prep+fill: xb, W-transpose, parallel scan, CSR fill ====
// 1024 blocks x 256 thr (4 blocks/CU guaranteed: LDS ~32B, VGPR<=128).
// Phase 1: xb bf16 convert (grid-stride) + W frag-major transpose (grid-stride)
//          + 49-block parallel scan partials over degree (degree IS the
//          edge_dst histogram -> no atomic histogram needed).
// Phase 2: 1-wave combine of the 49 chunk sums.
// Phase 3: distribute offsets -> rs, cursor (grid-stride).
// Phase 4: fill (round-9 proven 4-edge/thread, 50K low-contention counters).
// Replaces prep_k+fill_k (one launch boundary) and kills the single-block
// serial-scan tail that stretched prep (round-11: 67us at VALUBusy 3%).
__global__ __launch_bounds__(256, 4) void prepfill_k(
    const float* __restrict__ x, const float* __restrict__ W1,
    const float* __restrict__ W2, const float* __restrict__ degree,
    const int* __restrict__ esrc, const int* __restrict__ edst,
    unsigned short* __restrict__ xb, unsigned short* __restrict__ W1t,
    unsigned short* __restrict__ W2t, int* __restrict__ rs,
    int* __restrict__ cursor, int* __restrict__ bsum,
    int* __restrict__ boff, int* __restrict__ sorted_src) {
  cg::grid_group grid = cg::this_grid();
  __shared__ int wsum[4], woff[4];
  const int tid = threadIdx.x, lane = tid & 63, wv = tid >> 6;
  const int gtid = blockIdx.x * 256 + tid;
  const int gsize = gridDim.x * 256;

  // ---- phase 1a: scan partials, blocks 0..48 (1024 elems/block) ----
  if (blockIdx.x < 49) {
    int i = blockIdx.x * 1024 + tid * 4;
    int4 v = {0, 0, 0, 0};
    if (i + 3 < N_) {
      float4 d4 = *(const float4*)(degree + i);
      v.x = (int)(d4.x + 0.5f); v.y = (int)(d4.y + 0.5f);
      v.z = (int)(d4.z + 0.5f); v.w = (int)(d4.w + 0.5f);
    } else {
      if (i     < N_) v.x = (int)(degree[i]     + 0.5f);
      if (i + 1 < N_) v.y = (int)(degree[i + 1] + 0.5f);
      if (i + 2 < N_) v.z = (int)(degree[i + 2] + 0.5f);
      if (i + 3 < N_) v.w = (int)(degree[i + 3] + 0.5f);
    }
    int s4 = v.x + v.y + v.z + v.w;
    int s = s4;
#pragma unroll
    for (int off = 1; off < 64; off <<= 1) {
      int t = __shfl_up(s, off);
      if (lane >= off) s += t;
    }
    if (lane == 63) wsum[wv] = s;
    __syncthreads();
    if (tid == 0) {
      int a = 0;
#pragma unroll
      for (int w = 0; w < 4; ++w) { woff[w] = a; a += wsum[w]; }
      bsum[blockIdx.x] = a;
    }
    __syncthreads();
    int pre = woff[wv] + (s - s4);   // chunk-local exclusive prefix
    int e0 = pre, e1 = pre + v.x, e2 = e1 + v.y, e3 = e2 + v.z;
    if (i + 3 < N_) {
      int4 w0 = {e0, e1, e2, e3};
      *(int4*)(rs + i) = w0;
    } else {
      if (i     < N_) rs[i]     = e0;
      if (i + 1 < N_) rs[i + 1] = e1;
      if (i + 2 < N_) rs[i + 2] = e2;
      if (i + 3 < N_) rs[i + 3] = e3;
    }
  }
  // ---- phase 1b: x -> batch-interleaved bf16 xb[node][2][128] ----
  for (int t = gtid; t < 3200000; t += gsize) {
    int q = t * 4;
    int node = q >> 8;
    int rem = q & 255;
    int b = rem >> 7, c = rem & 127;
    float4 v = *(const float4*)(x + (size_t)b * (N_ * D_) + node * 128 + c);
    uint2 p = { (uint32_t)f2bf(v.x) | ((uint32_t)f2bf(v.y) << 16),
                (uint32_t)f2bf(v.z) | ((uint32_t)f2bf(v.w) << 16) };
    *(uint2*)(xb + q) = p;
  }
  // ---- phase 1c: W transpose -> fragment-major bf16.
  // Tile 16(n)x32(k); element (n,k) at lane=(n&15)+16*((k>>3)&3), j=k&7
  // -> wave b-frag load = base + lane*16B (one coalesced 1KB transaction).
  for (int t = gtid; t < 98304; t += gsize) {
    if (t < 65536) {
      int n = t >> 8, k = t & 255;
      int f = (n >> 4) * 8 + (k >> 5);
      int pos = ((n & 15) + ((k >> 3) & 3) * 16) * 8 + (k & 7);
      W1t[f * 512 + pos] = f2bf(W1[k * 256 + n]);
    } else {
      int t2 = t - 65536;
      int n = t2 >> 8, k = t2 & 255;
      int f = (n >> 4) * 8 + (k >> 5);
      int pos = ((n & 15) + ((k >> 3) & 3) * 16) * 8 + (k & 7);
      W2t[f * 512 + pos] = f2bf(W2[k * 128 + n]);
    }
  }
  grid.sync();
  // ---- phase 2: combine the 49 chunk sums (block 0, one wave) ----
  if (blockIdx.x == 0 && tid < 64) {
    int v = (tid < 49) ? bsum[tid] : 0;
    int s = v;
#pragma unroll
    for (int off = 1; off < 64; off <<= 1) {
      int t = __shfl_up(s, off);
      if (lane >= off) s += t;
    }
    boff[tid] = s - v;
  }
  grid.sync();
  // ---- phase 3: add chunk offsets -> rs, cursor ----
  for (int t = gtid; t < 12500; t += gsize) {
    int i = t * 4;
    int4 v = *(const int4*)(rs + i);
    int off = boff[i >> 10];
    v.x += off; v.y += off; v.z += off; v.w += off;
    *(int4*)(rs + i) = v;
    *(int4*)(cursor + i) = v;
  }
  if (gtid == 0) rs[N_] = E_;
  grid.sync();
  // ---- phase 4: CSR fill (counting sort), 4 edges/thread ----
  for (int t = gtid; t < E_ / 4; t += gsize) {
    int e4 = t * 4;
    int4 s4 = *(const int4*)(esrc + e4);
    int4 d4 = *(const int4*)(edst + e4);
    int p0 = atomicAdd(&cursor[d4.x], 1); sorted_src[p0] = s4.x;
    int p1 = atomicAdd(&cursor[d4.y], 1); sorted_src[p1] = s4.y;
    int p2 = atomicAdd(&cursor[d4.z], 1); sorted_src[p2] = s4.z;
    int p3 = atomicAdd(&cursor[d4.w], 1); sorted_src[p3] = s4.w;
  }
}

// ---------------- fused gather + dual LayerNorm -> h = [LN(x), LN(nb)] -----
// One wave per node. 32 lanes cover the full 512B row (uint4/lane), the two
// 32-lane halves (g=0/1) process 2 edges in parallel -> 8x16B loads in flight
// per lane.
__global__ __launch_bounds__(256) void gather_ln_k(
    const unsigned short* __restrict__ xb,
    const int* __restrict__ rs, const int* __restrict__ ss,
    const float* __restrict__ sn_g, const float* __restrict__ sn_b,
    const float* __restrict__ nn_g, const float* __restrict__ nn_b,
    unsigned short* __restrict__ h) {
  const int node = blockIdx.x * 4 + (threadIdx.x >> 6);
  const int lane = threadIdx.x & 63;
  const int g = lane >> 5;          // edge-parallel subgroup
  const int l32 = lane & 31;        // 16B chunk within the 512B row
  const int r0 = rs[node], r1 = rs[node + 1];
  const unsigned short* xrow = xb + l32 * 8;   // 8 bf16 per lane
  float acc[8] = {0.f, 0.f, 0.f, 0.f, 0.f, 0.f, 0.f, 0.f};
  for (int e = r0; e < r1; e += 16) {
    int idx[8];
#pragma unroll
    for (int j = 0; j < 8; ++j) {
      int ej = e + 2 * j + g;
      idx[j] = ss[(ej < r1) ? ej : r0];
    }
    uint4 v[8];
#pragma unroll
    for (int j = 0; j < 8; ++j)
      v[j] = *(const uint4*)(xrow + (size_t)idx[j] * 256);
#pragma unroll
    for (int j = 0; j < 8; ++j) {
      if (e + 2 * j + g < r1) {
        acc[0] += uasf(v[j].x << 16); acc[1] += uasf(v[j].x & 0xffff0000u);
        acc[2] += uasf(v[j].y << 16); acc[3] += uasf(v[j].y & 0xffff0000u);
        acc[4] += uasf(v[j].z << 16); acc[5] += uasf(v[j].z & 0xffff0000u);
        acc[6] += uasf(v[j].w << 16); acc[7] += uasf(v[j].w & 0xffff0000u);
      }
    }
  }
  // combine the two edge-parallel halves
#pragma unroll
  for (int k = 0; k < 8; ++k) acc[k] += __shfl_xor(acc[k], 32);
  const float invd = 1.0f / fmaxf((float)(r1 - r0), 1.0f);
  float nb[8];
#pragma unroll
  for (int k = 0; k < 8; ++k) nb[k] = acc[k] * invd;
  uint4 xq = *(const uint4*)(xrow + (size_t)node * 256);  // own row (bf16)
  float xv[8];
  xv[0] = uasf(xq.x << 16); xv[1] = uasf(xq.x & 0xffff0000u);
  xv[2] = uasf(xq.y << 16); xv[3] = uasf(xq.y & 0xffff0000u);
  xv[4] = uasf(xq.z << 16); xv[5] = uasf(xq.z & 0xffff0000u);
  xv[6] = uasf(xq.w << 16); xv[7] = uasf(xq.w & 0xffff0000u);
  float sx = 0.f, sxx = 0.f, sn = 0.f, snn = 0.f;
#pragma unroll
  for (int k = 0; k < 8; ++k) {
    sx += xv[k]; sxx += xv[k] * xv[k];
    sn += nb[k]; snn += nb[k] * nb[k];
  }
  // reduce within the 16-lane batch group (lanes [0,16) b0, [16,32) b1, etc.)
#pragma unroll
  for (int off = 1; off < 16; off <<= 1) {
    sx  += __shfl_xor(sx, off);  sxx += __shfl_xor(sxx, off);
    sn  += __shfl_xor(sn, off);  snn += __shfl_xor(snn, off);
  }
  const float r = 1.0f / 128.0f;
  float mx = sx * r, vx = fmaxf(sxx * r - mx * mx, 0.f);
  float mn = sn * r, vn = fmaxf(snn * r - mn * mn, 0.f);
  float rx = rsqrtf(vx + 1e-5f), rn = rsqrtf(vn + 1e-5f);
  const int c = (l32 & 15) * 8;
  // g==0 lanes write y = LN(x); g==1 lanes write z = LN(nb)
  const float* gp = g ? nn_g : sn_g;
  const float* bp = g ? nn_b : sn_b;
  float4 g0 = *(const float4*)(gp + c), g1 = *(const float4*)(gp + c + 4);
  float4 b0 = *(const float4*)(bp + c), b1v = *(const float4*)(bp + c + 4);
  float gw[8] = {g0.x, g0.y, g0.z, g0.w, g1.x, g1.y, g1.z, g1.w};
  float bw[8] = {b0.x, b0.y, b0.z, b0.w, b1v.x, b1v.y, b1v.z, b1v.w};
  float mu = g ? mn : mx;
  float rs_ = g ? rn : rx;
  float o[8];
#pragma unroll
  for (int k = 0; k < 8; ++k) {
    float s = g ? nb[k] : xv[k];
    o[k] = (s - mu) * rs_ * gw[k] + bw[k];
  }
  uint4 po;
  po.x = (uint32_t)f2bf(o[0]) | ((uint32_t)f2bf(o[1]) << 16);
  po.y = (uint32_t)f2bf(o[2]) | ((uint32_t)f2bf(o[3]) << 16);
  po.z = (uint32_t)f2bf(o[4]) | ((uint32_t)f2bf(o[5]) << 16);
  po.w = (uint32_t)f2bf(o[6]) | ((uint32_t)f2bf(o[7]) << 16);
  unsigned short* hr = h + ((size_t)(l32 >> 4) * N_ + node) * 256 + g * 128 + c;
  *(uint4*)hr = po;
}

// ---------------- fused MLP: out = GELU(h @ W1^T + b1) @ W2^T + b2 + x ------
// v7 (round-12 best, kept): BM=64, As 32KB + Hc 8KB = 40KB -> 4 blocks/CU,
// 16 waves/CU. Round-13's BM=32 (32 waves/CU) regressed: 2x blocks doubled
// W/L2 traffic (FETCH 51.6->65MB) and halved MFMA:load mix. Local optimum.
__global__ __launch_bounds__(256, 4) void fused_mlp_k(
    const unsigned short* __restrict__ A,      // h [M][256] bf16
    const unsigned short* __restrict__ W1t,    // frag-major [16x8 tiles][512]
    const unsigned short* __restrict__ W2t,    // frag-major [8x8 tiles][512]
    const float* __restrict__ b1,
    const float* __restrict__ b2,
    const float* __restrict__ resid,           // x fp32 [M][128]
    float* __restrict__ outp, int M) {
  __shared__ unsigned short As[64 * 256];    // 32768 B, swizzled: chunk ^ (row&7)
  __shared__ unsigned short Hc[64 * 64];     // 8192 B, swizzled: elem ^ ((row&7)<<3)
  const int tid = threadIdx.x;
  const int wave = tid >> 6, lane = tid & 63;
  const int wr = wave >> 1;        // 0..1: 32-row strip
  const int wc = wave & 1;         // 0/1: column half
  const int quad = lane >> 4, l15 = lane & 15;
  const int m0 = blockIdx.x * 64;
  // ---- stage A tile once: 64 rows x 32 16B-chunks, 8 iters x 256 thr ----
  {
    uint4 v[8];
#pragma unroll
    for (int it = 0; it < 8; ++it) {
      int id = it * 256 + tid;
      int r = id >> 5, c16 = id & 31;
      int gm = m0 + r;
      uint4 va = {0u, 0u, 0u, 0u};
      if (gm < M) va = *(const uint4*)(A + (size_t)gm * 256 + c16 * 8);
      v[it] = va;
    }
#pragma unroll
    for (int it = 0; it < 8; ++it) {
      int id = it * 256 + tid;
      int r = id >> 5, c16 = id & 31;
      *(uint4*)(&As[r * 256 + (c16 ^ (r & 7)) * 8]) = v[it];
    }
  }
  f32x4 acc2[2][4] = {};
  __syncthreads();
  for (int nc = 0; nc < 4; ++nc) {
    // ---- gemm1 chunk: 64 rows x 64 h1-cols; wave owns 32x32 ----
    f32x4 acc1[2][2] = {};
#pragma unroll
    for (int kc = 0; kc < 256; kc += 32) {
      bf16x8 a[2], b[2];
#pragma unroll
      for (int i = 0; i < 2; ++i) {
        int row = wr * 32 + i * 16 + l15;
        a[i] = *(const bf16x8*)(&As[row * 256 + ((kc + quad * 8) ^ ((row & 7) << 3))]);
      }
#pragma unroll
      for (int i = 0; i < 2; ++i) {
        int ftile = (nc * 4 + wc * 2 + i) * 8 + (kc >> 5);
        b[i] = *(const bf16x8*)(W1t + ftile * 512 + lane * 8);
      }
#pragma unroll
      for (int mi = 0; mi < 2; ++mi)
#pragma unroll
        for (int ni = 0; ni < 2; ++ni)
          acc1[mi][ni] = __builtin_amdgcn_mfma_f32_16x16x32_bf16(a[mi], b[ni], acc1[mi][ni], 0, 0, 0);
    }
    __syncthreads();   // prev iter's gemm2 finished reading Hc
    // ---- GELU(acc1 + b1) -> Hc (bf16, swizzled) ----
#pragma unroll
    for (int mi = 0; mi < 2; ++mi)
#pragma unroll
      for (int ni = 0; ni < 2; ++ni) {
        int col = wc * 32 + ni * 16 + l15;
        float bv = b1[nc * 64 + col];
#pragma unroll
        for (int rr = 0; rr < 4; ++rr) {
          int row = wr * 32 + mi * 16 + quad * 4 + rr;
          Hc[row * 64 + (col ^ ((row & 7) << 3))] = f2bf(fast_gelu(acc1[mi][ni][rr] + bv));
        }
      }
    __syncthreads();
    // ---- gemm2 partial: acc2 += Hc(64x64) @ W2[:, nc*64 .. +64]; 32x64/wave
#pragma unroll
    for (int kc = 0; kc < 64; kc += 32) {
      bf16x8 a[2], b[4];
#pragma unroll
      for (int i = 0; i < 2; ++i) {
        int row = wr * 32 + i * 16 + l15;
        a[i] = *(const bf16x8*)(&Hc[row * 64 + ((kc + quad * 8) ^ ((row & 7) << 3))]);
      }
#pragma unroll
      for (int i = 0; i < 4; ++i) {
        int ftile = (wc * 4 + i) * 8 + nc * 2 + (kc >> 5);
        b[i] = *(const bf16x8*)(W2t + ftile * 512 + lane * 8);
      }
#pragma unroll
      for (int mi = 0; mi < 2; ++mi)
#pragma unroll
        for (int ni = 0; ni < 4; ++ni)
          acc2[mi][ni] = __builtin_amdgcn_mfma_f32_16x16x32_bf16(a[mi], b[ni], acc2[mi][ni], 0, 0, 0);
    }
  }
  // ---- epilogue: + b2 + resid, fp32 out ----
#pragma unroll
  for (int mi = 0; mi < 2; ++mi)
#pragma unroll
    for (int ni = 0; ni < 4; ++ni) {
      int col = wc * 64 + ni * 16 + l15;
      float bv = b2[col];
#pragma unroll
      for (int rr = 0; rr < 4; ++rr) {
        int row = m0 + wr * 32 + mi * 16 + quad * 4 + rr;
        if (row < M) {
          float v = acc2[mi][ni][rr] + bv + resid[(size_t)row * 128 + col];
          outp[(size_t)row * 128 + col] = v;
        }
      }
    }
}

extern "C" void kernel_launch(void* const* d_in, const int* in_sizes, int n_in,
                              void* d_out, int out_size, void* d_ws, size_t ws_size,
                              hipStream_t stream) {
  const float* x      = (const float*)d_in[0];
  const int* esrc     = (const int*)d_in[1];
  const int* edst     = (const int*)d_in[2];
  const float* degree = (const float*)d_in[3];
  const float* sn_g   = (const float*)d_in[4];
  const float* sn_b   = (const float*)d_in[5];
  const float* nn_g   = (const float*)d_in[6];
  const float* nn_b   = (const float*)d_in[7];
  const float* W1     = (const float*)d_in[8];
  const float* b1     = (const float*)d_in[9];
  const float* W2     = (const float*)d_in[10];
  const float* b2     = (const float*)d_in[11];

  char* ws = (char*)d_ws;
  const size_t H_BYTES = (size_t)TOK * 256 * 2;          // 51.2 MB
  unsigned short* h = (unsigned short*)ws;               // [TOK][256] bf16
  // CSR + xb region:
  char* csr = ws + H_BYTES;
  int* bsum       = (int*)(csr);                          // 49 ints
  int* boff       = (int*)(csr + 4096);                   // 64 ints
  int* rs         = (int*)(csr + 400000);                 // 50001 ints
  int* cursor     = (int*)(csr + 600016);                 // 50000 ints
  int* sorted_src = (int*)(csr + 800512);                 // 800000 ints -> ends 4,000,512
  unsigned short* xb = (unsigned short*)(csr + 4194304);  // [N][2][128] bf16, 25.6 MB
  unsigned short* W1t = (unsigned short*)(ws + 2 * H_BYTES);
  unsigned short* W2t = W1t + 65536;

  void* args[] = {
    (void*)&x, (void*)&W1, (void*)&W2, (void*)&degree,
    (void*)&esrc, (void*)&edst,
    (void*)&xb, (void*)&W1t, (void*)&W2t,
    (void*)&rs, (void*)&cursor, (void*)&bsum, (void*)&boff,
    (void*)&sorted_src
  };
  hipLaunchCooperativeKernel((const void*)prepfill_k, dim3(1024), dim3(256),
                             args, 0, stream);
  gather_ln_k<<<N_ / 4, 256, 0, stream>>>(xb, rs, sorted_src,
                                          sn_g, sn_b, nn_g, nn_b, h);
  fused_mlp_k<<<(TOK + 63) / 64, 256, 0, stream>>>(h, W1t, W2t, b1, b2,
                                                   x, (float*)d_out, TOK);
}

// Round 15
// 299.291 us; speedup vs baseline: 2.1657x; 2.1657x over previous
//
#include <hip/hip_runtime.h>
#include <cstdint>

#define B_ 2
#define N_ 50000
#define D_ 128
#define E_ 800000
#define TOK 100000   // B_*N_

typedef __bf16 bf16x8 __attribute__((ext_vector_type(8)));
typedef float f32x4 __attribute__((ext_vector_type(4)));

__device__ __forceinline__ unsigned short f2bf(float f) {
  union { float f; uint32_t u; } v; v.f = f;
  uint32_t u = v.u;
  return (unsigned short)((u + 0x7FFFu + ((u >> 16) & 1u)) >> 16);
}
__device__ __forceinline__ float uasf(uint32_t u) {
  union { uint32_t u; float f; } v; v.u = u; return v.f;
}
// tanh-form GELU: v * sigmoid(1.5958*(v + 0.044715 v^3)); max |err| vs exact
// erf-GELU ~3e-4 << bf16 rounding of h1. Branch-free saturation.
__device__ __forceinline__ float fast_gelu(float v) {
  float p = v * (1.5957691f + 0.07135481f * v * v);
  return v * __builtin_amdgcn_rcpf(1.0f + __expf(-p));
}

// ---- fused prep (1024-thr blocks): xb build (blocks 0..3124),
// ---- W transpose (3125..3220), degree-scan -> rs,cursor (block 3221) -------
// degree (input) IS the edge_dst histogram -> no memset/atomic histogram.
// W1t/W2t stored FRAGMENT-MAJOR: 16(n)x32(k) tiles, element (n,k) at
// lane=(n&15)+16*((k>>3)&3), j=k&7 -> wave b-frag load = base + lane*16B.
__global__ __launch_bounds__(1024) void prep_k(
    const float* __restrict__ x, const float* __restrict__ W1,
    const float* __restrict__ W2, const float* __restrict__ degree,
    unsigned short* __restrict__ xb, unsigned short* __restrict__ W1t,
    unsigned short* __restrict__ W2t, int* __restrict__ rs,
    int* __restrict__ cursor) {
  __shared__ int wsum[16], woff[16], carry[2];
  const int blk = blockIdx.x;
  if (blk < 3125) {                // x -> batch-interleaved bf16 xb[node][2][128]
    int q = (blk * 1024 + threadIdx.x) * 4;
    int node = q >> 8;
    int rem = q & 255;
    int b = rem >> 7, c = rem & 127;
    float4 v = *(const float4*)(x + (size_t)b * (N_ * D_) + node * 128 + c);
    uint2 p = { (uint32_t)f2bf(v.x) | ((uint32_t)f2bf(v.y) << 16),
                (uint32_t)f2bf(v.z) | ((uint32_t)f2bf(v.w) << 16) };
    *(uint2*)(xb + q) = p;
  } else if (blk < 3221) {         // weight transpose -> fragment-major bf16
    int t = (blk - 3125) * 1024 + threadIdx.x;
    if (t < 65536) {
      int n = t >> 8, k = t & 255;
      int f = (n >> 4) * 8 + (k >> 5);
      int pos = ((n & 15) + ((k >> 3) & 3) * 16) * 8 + (k & 7);
      W1t[f * 512 + pos] = f2bf(W1[k * 256 + n]);
    } else {
      int t2 = t - 65536;
      int n = t2 >> 8, k = t2 & 255;
      int f = (n >> 4) * 8 + (k >> 5);
      int pos = ((n & 15) + ((k >> 3) & 3) * 16) * 8 + (k & 7);
      W2t[f * 512 + pos] = f2bf(W2[k * 128 + n]);
    }
  } else {                         // block 3221: exclusive scan of degree
    const int tid = threadIdx.x, lane = tid & 63, wv = tid >> 6;
    if (tid == 0) carry[0] = 0;
    int p = 0;
    __syncthreads();
    for (int base = 0; base < N_; base += 4096) {
      int i = base + tid * 4;
      int4 v = {0, 0, 0, 0};
      if (i + 3 < N_) {
        float4 d4 = *(const float4*)(degree + i);
        v.x = (int)(d4.x + 0.5f); v.y = (int)(d4.y + 0.5f);
        v.z = (int)(d4.z + 0.5f); v.w = (int)(d4.w + 0.5f);
      } else {
        if (i     < N_) v.x = (int)(degree[i]     + 0.5f);
        if (i + 1 < N_) v.y = (int)(degree[i + 1] + 0.5f);
        if (i + 2 < N_) v.z = (int)(degree[i + 2] + 0.5f);
        if (i + 3 < N_) v.w = (int)(degree[i + 3] + 0.5f);
      }
      int s4 = v.x + v.y + v.z + v.w;
      int s = s4;
#pragma unroll
      for (int off = 1; off < 64; off <<= 1) {
        int t = __shfl_up(s, off);
        if (lane >= off) s += t;
      }
      if (lane == 63) wsum[wv] = s;
      __syncthreads();
      if (tid == 0) {
        int a = 0;
#pragma unroll
        for (int w = 0; w < 16; ++w) { woff[w] = a; a += wsum[w]; }
        carry[p ^ 1] = carry[p] + a;
      }
      __syncthreads();
      int pre = carry[p] + woff[wv] + (s - s4);
      int e0 = pre, e1 = pre + v.x, e2 = e1 + v.y, e3 = e2 + v.z;
      if (i + 3 < N_) {
        int4 w0 = {e0, e1, e2, e3};
        *(int4*)(rs + i) = w0;
        *(int4*)(cursor + i) = w0;
      } else {
        if (i     < N_) { rs[i]     = e0; cursor[i]     = e0; }
        if (i + 1 < N_) { rs[i + 1] = e1; cursor[i + 1] = e1; }
        if (i + 2 < N_) { rs[i + 2] = e2; cursor[i + 2] = e2; }
        if (i + 3 < N_) { rs[i + 3] = e3; cursor[i + 3] = e3; }
      }
      p ^= 1;
    }
    if (tid == 0) rs[N_] = E_;
  }
}

// ---------------- CSR build: counting-sort edge srcs by dst -----------------
// Round-9 proven version: 4 edges/thread, 50K counters (low contention).
__global__ __launch_bounds__(256) void fill_k(const int* __restrict__ esrc,
                                              const int* __restrict__ edst,
                                              int* __restrict__ cursor,
                                              int* __restrict__ sorted_src) {
  int e4 = (blockIdx.x * 256 + threadIdx.x) * 4;
  if (e4 < E_) {
    int4 s4 = *(const int4*)(esrc + e4);
    int4 d4 = *(const int4*)(edst + e4);
    int p0 = atomicAdd(&cursor[d4.x], 1); sorted_src[p0] = s4.x;
    int p1 = atomicAdd(&cursor[d4.y], 1); sorted_src[p1] = s4.y;
    int p2 = atomicAdd(&cursor[d4.z], 1); sorted_src[p2] = s4.z;
    int p3 = atomicAdd(&cursor[d4.w], 1); sorted_src[p3] = s4.w;
  }
}

// ---------------- fused gather + dual LayerNorm -> h = [LN(x), LN(nb)] -----
// One wave per node. 32 lanes cover the full 512B row (uint4/lane), the two
// 32-lane halves (g=0/1) process 2 edges in parallel -> 8x16B loads in flight
// per lane.
__global__ __launch_bounds__(256) void gather_ln_k(
    const unsigned short* __restrict__ xb,
    const int* __restrict__ rs, const int* __restrict__ ss,
    const float* __restrict__ sn_g, const float* __restrict__ sn_b,
    const float* __restrict__ nn_g, const float* __restrict__ nn_b,
    unsigned short* __restrict__ h) {
  const int node = blockIdx.x * 4 + (threadIdx.x >> 6);
  const int lane = threadIdx.x & 63;
  const int g = lane >> 5;          // edge-parallel subgroup
  const int l32 = lane & 31;        // 16B chunk within the 512B row
  const int r0 = rs[node], r1 = rs[node + 1];
  const unsigned short* xrow = xb + l32 * 8;   // 8 bf16 per lane
  float acc[8] = {0.f, 0.f, 0.f, 0.f, 0.f, 0.f, 0.f, 0.f};
  for (int e = r0; e < r1; e += 16) {
    int idx[8];
#pragma unroll
    for (int j = 0; j < 8; ++j) {
      int ej = e + 2 * j + g;
      idx[j] = ss[(ej < r1) ? ej : r0];
    }
    uint4 v[8];
#pragma unroll
    for (int j = 0; j < 8; ++j)
      v[j] = *(const uint4*)(xrow + (size_t)idx[j] * 256);
#pragma unroll
    for (int j = 0; j < 8; ++j) {
      if (e + 2 * j + g < r1) {
        acc[0] += uasf(v[j].x << 16); acc[1] += uasf(v[j].x & 0xffff0000u);
        acc[2] += uasf(v[j].y << 16); acc[3] += uasf(v[j].y & 0xffff0000u);
        acc[4] += uasf(v[j].z << 16); acc[5] += uasf(v[j].z & 0xffff0000u);
        acc[6] += uasf(v[j].w << 16); acc[7] += uasf(v[j].w & 0xffff0000u);
      }
    }
  }
  // combine the two edge-parallel halves
#pragma unroll
  for (int k = 0; k < 8; ++k) acc[k] += __shfl_xor(acc[k], 32);
  const float invd = 1.0f / fmaxf((float)(r1 - r0), 1.0f);
  float nb[8];
#pragma unroll
  for (int k = 0; k < 8; ++k) nb[k] = acc[k] * invd;
  uint4 xq = *(const uint4*)(xrow + (size_t)node * 256);  // own row (bf16)
  float xv[8];
  xv[0] = uasf(xq.x << 16); xv[1] = uasf(xq.x & 0xffff0000u);
  xv[2] = uasf(xq.y << 16); xv[3] = uasf(xq.y & 0xffff0000u);
  xv[4] = uasf(xq.z << 16); xv[5] = uasf(xq.z & 0xffff0000u);
  xv[6] = uasf(xq.w << 16); xv[7] = uasf(xq.w & 0xffff0000u);
  float sx = 0.f, sxx = 0.f, sn = 0.f, snn = 0.f;
#pragma unroll
  for (int k = 0; k < 8; ++k) {
    sx += xv[k]; sxx += xv[k] * xv[k];
    sn += nb[k]; snn += nb[k] * nb[k];
  }
  // reduce within the 16-lane batch group (lanes [0,16) b0, [16,32) b1, etc.)
#pragma unroll
  for (int off = 1; off < 16; off <<= 1) {
    sx  += __shfl_xor(sx, off);  sxx += __shfl_xor(sxx, off);
    sn  += __shfl_xor(sn, off);  snn += __shfl_xor(snn, off);
  }
  const float r = 1.0f / 128.0f;
  float mx = sx * r, vx = fmaxf(sxx * r - mx * mx, 0.f);
  float mn = sn * r, vn = fmaxf(snn * r - mn * mn, 0.f);
  float rx = rsqrtf(vx + 1e-5f), rn = rsqrtf(vn + 1e-5f);
  const int c = (l32 & 15) * 8;
  // g==0 lanes write y = LN(x); g==1 lanes write z = LN(nb)
  const float* gp = g ? nn_g : sn_g;
  const float* bp = g ? nn_b : sn_b;
  float4 g0 = *(const float4*)(gp + c), g1 = *(const float4*)(gp + c + 4);
  float4 b0 = *(const float4*)(bp + c), b1v = *(const float4*)(bp + c + 4);
  float gw[8] = {g0.x, g0.y, g0.z, g0.w, g1.x, g1.y, g1.z, g1.w};
  float bw[8] = {b0.x, b0.y, b0.z, b0.w, b1v.x, b1v.y, b1v.z, b1v.w};
  float mu = g ? mn : mx;
  float rs_ = g ? rn : rx;
  float o[8];
#pragma unroll
  for (int k = 0; k < 8; ++k) {
    float s = g ? nb[k] : xv[k];
    o[k] = (s - mu) * rs_ * gw[k] + bw[k];
  }
  uint4 po;
  po.x = (uint32_t)f2bf(o[0]) | ((uint32_t)f2bf(o[1]) << 16);
  po.y = (uint32_t)f2bf(o[2]) | ((uint32_t)f2bf(o[3]) << 16);
  po.z = (uint32_t)f2bf(o[4]) | ((uint32_t)f2bf(o[5]) << 16);
  po.w = (uint32_t)f2bf(o[6]) | ((uint32_t)f2bf(o[7]) << 16);
  unsigned short* hr = h + ((size_t)(l32 >> 4) * N_ + node) * 256 + g * 128 + c;
  *(uint4*)hr = po;
}

// ---------------- fused MLP: out = GELU(h @ W1^T + b1) @ W2^T + b2 + x ------
// v7 (round-12 best, kept): BM=64, As 32KB + Hc 8KB = 40KB -> 4 blocks/CU,
// 16 waves/CU. BM=32 (32 waves/CU) regressed: 2x blocks doubled W/L2 traffic
// and halved MFMA:load mix. BM=128 (2 blocks/CU) regressed: TLP-starved.
__global__ __launch_bounds__(256, 4) void fused_mlp_k(
    const unsigned short* __restrict__ A,      // h [M][256] bf16
    const unsigned short* __restrict__ W1t,    // frag-major [16x8 tiles][512]
    const unsigned short* __restrict__ W2t,    // frag-major [8x8 tiles][512]
    const float* __restrict__ b1,
    const float* __restrict__ b2,
    const float* __restrict__ resid,           // x fp32 [M][128]
    float* __restrict__ outp, int M) {
  __shared__ unsigned short As[64 * 256];    // 32768 B, swizzled: chunk ^ (row&7)
  __shared__ unsigned short Hc[64 * 64];     // 8192 B, swizzled: elem ^ ((row&7)<<3)
  const int tid = threadIdx.x;
  const int wave = tid >> 6, lane = tid & 63;
  const int wr = wave >> 1;        // 0..1: 32-row strip
  const int wc = wave & 1;         // 0/1: column half
  const int quad = lane >> 4, l15 = lane & 15;
  const int m0 = blockIdx.x * 64;
  // ---- stage A tile once: 64 rows x 32 16B-chunks, 8 iters x 256 thr ----
  {
    uint4 v[8];
#pragma unroll
    for (int it = 0; it < 8; ++it) {
      int id = it * 256 + tid;
      int r = id >> 5, c16 = id & 31;
      int gm = m0 + r;
      uint4 va = {0u, 0u, 0u, 0u};
      if (gm < M) va = *(const uint4*)(A + (size_t)gm * 256 + c16 * 8);
      v[it] = va;
    }
#pragma unroll
    for (int it = 0; it < 8; ++it) {
      int id = it * 256 + tid;
      int r = id >> 5, c16 = id & 31;
      *(uint4*)(&As[r * 256 + (c16 ^ (r & 7)) * 8]) = v[it];
    }
  }
  f32x4 acc2[2][4] = {};
  __syncthreads();
  for (int nc = 0; nc < 4; ++nc) {
    // ---- gemm1 chunk: 64 rows x 64 h1-cols; wave owns 32x32 ----
    f32x4 acc1[2][2] = {};
#pragma unroll
    for (int kc = 0; kc < 256; kc += 32) {
      bf16x8 a[2], b[2];
#pragma unroll
      for (int i = 0; i < 2; ++i) {
        int row = wr * 32 + i * 16 + l15;
        a[i] = *(const bf16x8*)(&As[row * 256 + ((kc + quad * 8) ^ ((row & 7) << 3))]);
      }
#pragma unroll
      for (int i = 0; i < 2; ++i) {
        int ftile = (nc * 4 + wc * 2 + i) * 8 + (kc >> 5);
        b[i] = *(const bf16x8*)(W1t + ftile * 512 + lane * 8);
      }
#pragma unroll
      for (int mi = 0; mi < 2; ++mi)
#pragma unroll
        for (int ni = 0; ni < 2; ++ni)
          acc1[mi][ni] = __builtin_amdgcn_mfma_f32_16x16x32_bf16(a[mi], b[ni], acc1[mi][ni], 0, 0, 0);
    }
    __syncthreads();   // prev iter's gemm2 finished reading Hc
    // ---- GELU(acc1 + b1) -> Hc (bf16, swizzled) ----
#pragma unroll
    for (int mi = 0; mi < 2; ++mi)
#pragma unroll
      for (int ni = 0; ni < 2; ++ni) {
        int col = wc * 32 + ni * 16 + l15;
        float bv = b1[nc * 64 + col];
#pragma unroll
        for (int rr = 0; rr < 4; ++rr) {
          int row = wr * 32 + mi * 16 + quad * 4 + rr;
          Hc[row * 64 + (col ^ ((row & 7) << 3))] = f2bf(fast_gelu(acc1[mi][ni][rr] + bv));
        }
      }
    __syncthreads();
    // ---- gemm2 partial: acc2 += Hc(64x64) @ W2[:, nc*64 .. +64]; 32x64/wave
#pragma unroll
    for (int kc = 0; kc < 64; kc += 32) {
      bf16x8 a[2], b[4];
#pragma unroll
      for (int i = 0; i < 2; ++i) {
        int row = wr * 32 + i * 16 + l15;
        a[i] = *(const bf16x8*)(&Hc[row * 64 + ((kc + quad * 8) ^ ((row & 7) << 3))]);
      }
#pragma unroll
      for (int i = 0; i < 4; ++i) {
        int ftile = (wc * 4 + i) * 8 + nc * 2 + (kc >> 5);
        b[i] = *(const bf16x8*)(W2t + ftile * 512 + lane * 8);
      }
#pragma unroll
      for (int mi = 0; mi < 2; ++mi)
#pragma unroll
        for (int ni = 0; ni < 4; ++ni)
          acc2[mi][ni] = __builtin_amdgcn_mfma_f32_16x16x32_bf16(a[mi], b[ni], acc2[mi][ni], 0, 0, 0);
    }
  }
  // ---- epilogue: + b2 + resid, fp32 out ----
#pragma unroll
  for (int mi = 0; mi < 2; ++mi)
#pragma unroll
    for (int ni = 0; ni < 4; ++ni) {
      int col = wc * 64 + ni * 16 + l15;
      float bv = b2[col];
#pragma unroll
      for (int rr = 0; rr < 4; ++rr) {
        int row = m0 + wr * 32 + mi * 16 + quad * 4 + rr;
        if (row < M) {
          float v = acc2[mi][ni][rr] + bv + resid[(size_t)row * 128 + col];
          outp[(size_t)row * 128 + col] = v;
        }
      }
    }
}

extern "C" void kernel_launch(void* const* d_in, const int* in_sizes, int n_in,
                              void* d_out, int out_size, void* d_ws, size_t ws_size,
                              hipStream_t stream) {
  const float* x      = (const float*)d_in[0];
  const int* esrc     = (const int*)d_in[1];
  const int* edst     = (const int*)d_in[2];
  const float* degree = (const float*)d_in[3];
  const float* sn_g   = (const float*)d_in[4];
  const float* sn_b   = (const float*)d_in[5];
  const float* nn_g   = (const float*)d_in[6];
  const float* nn_b   = (const float*)d_in[7];
  const float* W1     = (const float*)d_in[8];
  const float* b1     = (const float*)d_in[9];
  const float* W2     = (const float*)d_in[10];
  const float* b2     = (const float*)d_in[11];

  char* ws = (char*)d_ws;
  const size_t H_BYTES = (size_t)TOK * 256 * 2;          // 51.2 MB
  unsigned short* h = (unsigned short*)ws;               // [TOK][256] bf16
  // CSR + xb region:
  char* csr = ws + H_BYTES;
  int* rs         = (int*)(csr + 400000);                 // 50001 ints
  int* cursor     = (int*)(csr + 600016);                 // 50000 ints
  int* sorted_src = (int*)(csr + 800512);                 // 800000 ints -> ends 4,000,512
  unsigned short* xb = (unsigned short*)(csr + 4194304);  // [N][2][128] bf16, 25.6 MB
  unsigned short* W1t = (unsigned short*)(ws + 2 * H_BYTES);
  unsigned short* W2t = W1t + 65536;

  prep_k<<<3222, 1024, 0, stream>>>(x, W1, W2, degree, xb, W1t, W2t, rs, cursor);
  fill_k<<<(E_ / 4 + 255) / 256, 256, 0, stream>>>(esrc, edst, cursor, sorted_src);
  gather_ln_k<<<N_ / 4, 256, 0, stream>>>(xb, rs, sorted_src,
                                          sn_g, sn_b, nn_g, nn_b, h);
  fused_mlp_k<<<(TOK + 63) / 64, 256, 0, stream>>>(h, W1t, W2t, b1, b2,
                                                   x, (float*)d_out, TOK);
}

// Round 16
// 292.887 us; speedup vs baseline: 2.2130x; 1.0219x over previous
//
#include <hip/hip_runtime.h>
#include <cstdint>

#define B_ 2
#define N_ 50000
#define D_ 128
#define E_ 800000
#define TOK 100000   // B_*N_
#define CAP 64       // bucket capacity; deg ~ Poisson(16), P(>=64) ~ 2e-18

typedef __bf16 bf16x8 __attribute__((ext_vector_type(8)));
typedef float f32x4 __attribute__((ext_vector_type(4)));

__device__ __forceinline__ unsigned short f2bf(float f) {
  union { float f; uint32_t u; } v; v.f = f;
  uint32_t u = v.u;
  return (unsigned short)((u + 0x7FFFu + ((u >> 16) & 1u)) >> 16);
}
__device__ __forceinline__ float uasf(uint32_t u) {
  union { uint32_t u; float f; } v; v.u = u; return v.f;
}
// tanh-form GELU: v * sigmoid(1.5958*(v + 0.044715 v^3)); max |err| vs exact
// erf-GELU ~3e-4 << bf16 rounding of h1. Branch-free saturation.
__device__ __forceinline__ float fast_gelu(float v) {
  float p = v * (1.5957691f + 0.07135481f * v * v);
  return v * __builtin_amdgcn_rcpf(1.0f + __expf(-p));
}

// ---- prep (1024-thr blocks): xb build (blocks 0..3124),
// ---- W transpose (3125..3220). NO scan: fixed-capacity bucket CSR means
// ---- gather derives row bounds from degree directly (r0 = node*CAP).
// W1t/W2t stored FRAGMENT-MAJOR: 16(n)x32(k) tiles, element (n,k) at
// lane=(n&15)+16*((k>>3)&3), j=k&7 -> wave b-frag load = base + lane*16B.
__global__ __launch_bounds__(1024) void prep_k(
    const float* __restrict__ x, const float* __restrict__ W1,
    const float* __restrict__ W2,
    unsigned short* __restrict__ xb, unsigned short* __restrict__ W1t,
    unsigned short* __restrict__ W2t) {
  const int blk = blockIdx.x;
  if (blk < 3125) {                // x -> batch-interleaved bf16 xb[node][2][128]
    int q = (blk * 1024 + threadIdx.x) * 4;
    int node = q >> 8;
    int rem = q & 255;
    int b = rem >> 7, c = rem & 127;
    float4 v = *(const float4*)(x + (size_t)b * (N_ * D_) + node * 128 + c);
    uint2 p = { (uint32_t)f2bf(v.x) | ((uint32_t)f2bf(v.y) << 16),
                (uint32_t)f2bf(v.z) | ((uint32_t)f2bf(v.w) << 16) };
    *(uint2*)(xb + q) = p;
  } else {                         // weight transpose -> fragment-major bf16
    int t = (blk - 3125) * 1024 + threadIdx.x;
    if (t < 65536) {
      int n = t >> 8, k = t & 255;
      int f = (n >> 4) * 8 + (k >> 5);
      int pos = ((n & 15) + ((k >> 3) & 3) * 16) * 8 + (k & 7);
      W1t[f * 512 + pos] = f2bf(W1[k * 256 + n]);
    } else {
      int t2 = t - 65536;
      int n = t2 >> 8, k = t2 & 255;
      int f = (n >> 4) * 8 + (k >> 5);
      int pos = ((n & 15) + ((k >> 3) & 3) * 16) * 8 + (k & 7);
      W2t[f * 512 + pos] = f2bf(W2[k * 128 + n]);
    }
  }
}

// ---------------- bucket-CSR build: counting-sort into fixed slots ----------
// 4 edges/thread, 50K counters (low contention, round-9 proven form).
// No scan dependency: slot = dst*CAP + atomicAdd(&cnt[dst],1).
__global__ __launch_bounds__(256) void fill_k(const int* __restrict__ esrc,
                                              const int* __restrict__ edst,
                                              int* __restrict__ cnt,
                                              int* __restrict__ bucket) {
  int e4 = (blockIdx.x * 256 + threadIdx.x) * 4;
  if (e4 < E_) {
    int4 s4 = *(const int4*)(esrc + e4);
    int4 d4 = *(const int4*)(edst + e4);
    int p0 = atomicAdd(&cnt[d4.x], 1); bucket[d4.x * CAP + p0] = s4.x;
    int p1 = atomicAdd(&cnt[d4.y], 1); bucket[d4.y * CAP + p1] = s4.y;
    int p2 = atomicAdd(&cnt[d4.z], 1); bucket[d4.z * CAP + p2] = s4.z;
    int p3 = atomicAdd(&cnt[d4.w], 1); bucket[d4.w * CAP + p3] = s4.w;
  }
}

// ---------------- fused gather + dual LayerNorm -> h = [LN(x), LN(nb)] -----
// One wave per node. 32 lanes cover the full 512B row (uint4/lane), the two
// 32-lane halves (g=0/1) process 2 edges in parallel -> 8x16B loads in flight
// per lane. Row bounds from degree (input): r0 = node*CAP, r1 = r0 + deg.
__global__ __launch_bounds__(256) void gather_ln_k(
    const unsigned short* __restrict__ xb,
    const float* __restrict__ degree, const int* __restrict__ ss,
    const float* __restrict__ sn_g, const float* __restrict__ sn_b,
    const float* __restrict__ nn_g, const float* __restrict__ nn_b,
    unsigned short* __restrict__ h) {
  const int node = blockIdx.x * 4 + (threadIdx.x >> 6);
  const int lane = threadIdx.x & 63;
  const int g = lane >> 5;          // edge-parallel subgroup
  const int l32 = lane & 31;        // 16B chunk within the 512B row
  const int deg = (int)(degree[node] + 0.5f);
  const int r0 = node * CAP, r1 = r0 + deg;
  const unsigned short* xrow = xb + l32 * 8;   // 8 bf16 per lane
  float acc[8] = {0.f, 0.f, 0.f, 0.f, 0.f, 0.f, 0.f, 0.f};
  for (int e = r0; e < r1; e += 16) {
    int idx[8];
#pragma unroll
    for (int j = 0; j < 8; ++j) {
      int ej = e + 2 * j + g;
      idx[j] = ss[(ej < r1) ? ej : r0];
    }
    uint4 v[8];
#pragma unroll
    for (int j = 0; j < 8; ++j)
      v[j] = *(const uint4*)(xrow + (size_t)idx[j] * 256);
#pragma unroll
    for (int j = 0; j < 8; ++j) {
      if (e + 2 * j + g < r1) {
        acc[0] += uasf(v[j].x << 16); acc[1] += uasf(v[j].x & 0xffff0000u);
        acc[2] += uasf(v[j].y << 16); acc[3] += uasf(v[j].y & 0xffff0000u);
        acc[4] += uasf(v[j].z << 16); acc[5] += uasf(v[j].z & 0xffff0000u);
        acc[6] += uasf(v[j].w << 16); acc[7] += uasf(v[j].w & 0xffff0000u);
      }
    }
  }
  // combine the two edge-parallel halves
#pragma unroll
  for (int k = 0; k < 8; ++k) acc[k] += __shfl_xor(acc[k], 32);
  const float invd = 1.0f / fmaxf((float)deg, 1.0f);
  float nb[8];
#pragma unroll
  for (int k = 0; k < 8; ++k) nb[k] = acc[k] * invd;
  uint4 xq = *(const uint4*)(xrow + (size_t)node * 256);  // own row (bf16)
  float xv[8];
  xv[0] = uasf(xq.x << 16); xv[1] = uasf(xq.x & 0xffff0000u);
  xv[2] = uasf(xq.y << 16); xv[3] = uasf(xq.y & 0xffff0000u);
  xv[4] = uasf(xq.z << 16); xv[5] = uasf(xq.z & 0xffff0000u);
  xv[6] = uasf(xq.w << 16); xv[7] = uasf(xq.w & 0xffff0000u);
  float sx = 0.f, sxx = 0.f, sn = 0.f, snn = 0.f;
#pragma unroll
  for (int k = 0; k < 8; ++k) {
    sx += xv[k]; sxx += xv[k] * xv[k];
    sn += nb[k]; snn += nb[k] * nb[k];
  }
  // reduce within the 16-lane batch group (lanes [0,16) b0, [16,32) b1, etc.)
#pragma unroll
  for (int off = 1; off < 16; off <<= 1) {
    sx  += __shfl_xor(sx, off);  sxx += __shfl_xor(sxx, off);
    sn  += __shfl_xor(sn, off);  snn += __shfl_xor(snn, off);
  }
  const float r = 1.0f / 128.0f;
  float mx = sx * r, vx = fmaxf(sxx * r - mx * mx, 0.f);
  float mn = sn * r, vn = fmaxf(snn * r - mn * mn, 0.f);
  float rx = rsqrtf(vx + 1e-5f), rn = rsqrtf(vn + 1e-5f);
  const int c = (l32 & 15) * 8;
  // g==0 lanes write y = LN(x); g==1 lanes write z = LN(nb)
  const float* gp = g ? nn_g : sn_g;
  const float* bp = g ? nn_b : sn_b;
  float4 g0 = *(const float4*)(gp + c), g1 = *(const float4*)(gp + c + 4);
  float4 b0 = *(const float4*)(bp + c), b1v = *(const float4*)(bp + c + 4);
  float gw[8] = {g0.x, g0.y, g0.z, g0.w, g1.x, g1.y, g1.z, g1.w};
  float bw[8] = {b0.x, b0.y, b0.z, b0.w, b1v.x, b1v.y, b1v.z, b1v.w};
  float mu = g ? mn : mx;
  float rs_ = g ? rn : rx;
  float o[8];
#pragma unroll
  for (int k = 0; k < 8; ++k) {
    float s = g ? nb[k] : xv[k];
    o[k] = (s - mu) * rs_ * gw[k] + bw[k];
  }
  uint4 po;
  po.x = (uint32_t)f2bf(o[0]) | ((uint32_t)f2bf(o[1]) << 16);
  po.y = (uint32_t)f2bf(o[2]) | ((uint32_t)f2bf(o[3]) << 16);
  po.z = (uint32_t)f2bf(o[4]) | ((uint32_t)f2bf(o[5]) << 16);
  po.w = (uint32_t)f2bf(o[6]) | ((uint32_t)f2bf(o[7]) << 16);
  unsigned short* hr = h + ((size_t)(l32 >> 4) * N_ + node) * 256 + g * 128 + c;
  *(uint4*)hr = po;
}

// ---------------- fused MLP: out = GELU(h @ W1^T + b1) @ W2^T + b2 + x ------
// v7 (round-12 best, kept): BM=64, As 32KB + Hc 8KB = 40KB -> 4 blocks/CU,
// 16 waves/CU. BM=32 (32 waves/CU) regressed: 2x blocks doubled W/L2 traffic
// and halved MFMA:load mix. BM=128 (2 blocks/CU) regressed: TLP-starved.
__global__ __launch_bounds__(256, 4) void fused_mlp_k(
    const unsigned short* __restrict__ A,      // h [M][256] bf16
    const unsigned short* __restrict__ W1t,    // frag-major [16x8 tiles][512]
    const unsigned short* __restrict__ W2t,    // frag-major [8x8 tiles][512]
    const float* __restrict__ b1,
    const float* __restrict__ b2,
    const float* __restrict__ resid,           // x fp32 [M][128]
    float* __restrict__ outp, int M) {
  __shared__ unsigned short As[64 * 256];    // 32768 B, swizzled: chunk ^ (row&7)
  __shared__ unsigned short Hc[64 * 64];     // 8192 B, swizzled: elem ^ ((row&7)<<3)
  const int tid = threadIdx.x;
  const int wave = tid >> 6, lane = tid & 63;
  const int wr = wave >> 1;        // 0..1: 32-row strip
  const int wc = wave & 1;         // 0/1: column half
  const int quad = lane >> 4, l15 = lane & 15;
  const int m0 = blockIdx.x * 64;
  // ---- stage A tile once: 64 rows x 32 16B-chunks, 8 iters x 256 thr ----
  {
    uint4 v[8];
#pragma unroll
    for (int it = 0; it < 8; ++it) {
      int id = it * 256 + tid;
      int r = id >> 5, c16 = id & 31;
      int gm = m0 + r;
      uint4 va = {0u, 0u, 0u, 0u};
      if (gm < M) va = *(const uint4*)(A + (size_t)gm * 256 + c16 * 8);
      v[it] = va;
    }
#pragma unroll
    for (int it = 0; it < 8; ++it) {
      int id = it * 256 + tid;
      int r = id >> 5, c16 = id & 31;
      *(uint4*)(&As[r * 256 + (c16 ^ (r & 7)) * 8]) = v[it];
    }
  }
  f32x4 acc2[2][4] = {};
  __syncthreads();
  for (int nc = 0; nc < 4; ++nc) {
    // ---- gemm1 chunk: 64 rows x 64 h1-cols; wave owns 32x32 ----
    f32x4 acc1[2][2] = {};
#pragma unroll
    for (int kc = 0; kc < 256; kc += 32) {
      bf16x8 a[2], b[2];
#pragma unroll
      for (int i = 0; i < 2; ++i) {
        int row = wr * 32 + i * 16 + l15;
        a[i] = *(const bf16x8*)(&As[row * 256 + ((kc + quad * 8) ^ ((row & 7) << 3))]);
      }
#pragma unroll
      for (int i = 0; i < 2; ++i) {
        int ftile = (nc * 4 + wc * 2 + i) * 8 + (kc >> 5);
        b[i] = *(const bf16x8*)(W1t + ftile * 512 + lane * 8);
      }
#pragma unroll
      for (int mi = 0; mi < 2; ++mi)
#pragma unroll
        for (int ni = 0; ni < 2; ++ni)
          acc1[mi][ni] = __builtin_amdgcn_mfma_f32_16x16x32_bf16(a[mi], b[ni], acc1[mi][ni], 0, 0, 0);
    }
    __syncthreads();   // prev iter's gemm2 finished reading Hc
    // ---- GELU(acc1 + b1) -> Hc (bf16, swizzled) ----
#pragma unroll
    for (int mi = 0; mi < 2; ++mi)
#pragma unroll
      for (int ni = 0; ni < 2; ++ni) {
        int col = wc * 32 + ni * 16 + l15;
        float bv = b1[nc * 64 + col];
#pragma unroll
        for (int rr = 0; rr < 4; ++rr) {
          int row = wr * 32 + mi * 16 + quad * 4 + rr;
          Hc[row * 64 + (col ^ ((row & 7) << 3))] = f2bf(fast_gelu(acc1[mi][ni][rr] + bv));
        }
      }
    __syncthreads();
    // ---- gemm2 partial: acc2 += Hc(64x64) @ W2[:, nc*64 .. +64]; 32x64/wave
#pragma unroll
    for (int kc = 0; kc < 64; kc += 32) {
      bf16x8 a[2], b[4];
#pragma unroll
      for (int i = 0; i < 2; ++i) {
        int row = wr * 32 + i * 16 + l15;
        a[i] = *(const bf16x8*)(&Hc[row * 64 + ((kc + quad * 8) ^ ((row & 7) << 3))]);
      }
#pragma unroll
      for (int i = 0; i < 4; ++i) {
        int ftile = (wc * 4 + i) * 8 + nc * 2 + (kc >> 5);
        b[i] = *(const bf16x8*)(W2t + ftile * 512 + lane * 8);
      }
#pragma unroll
      for (int mi = 0; mi < 2; ++mi)
#pragma unroll
        for (int ni = 0; ni < 4; ++ni)
          acc2[mi][ni] = __builtin_amdgcn_mfma_f32_16x16x32_bf16(a[mi], b[ni], acc2[mi][ni], 0, 0, 0);
    }
  }
  // ---- epilogue: + b2 + resid, fp32 out ----
#pragma unroll
  for (int mi = 0; mi < 2; ++mi)
#pragma unroll
    for (int ni = 0; ni < 4; ++ni) {
      int col = wc * 64 + ni * 16 + l15;
      float bv = b2[col];
#pragma unroll
      for (int rr = 0; rr < 4; ++rr) {
        int row = m0 + wr * 32 + mi * 16 + quad * 4 + rr;
        if (row < M) {
          float v = acc2[mi][ni][rr] + bv + resid[(size_t)row * 128 + col];
          outp[(size_t)row * 128 + col] = v;
        }
      }
    }
}

extern "C" void kernel_launch(void* const* d_in, const int* in_sizes, int n_in,
                              void* d_out, int out_size, void* d_ws, size_t ws_size,
                              hipStream_t stream) {
  const float* x      = (const float*)d_in[0];
  const int* esrc     = (const int*)d_in[1];
  const int* edst     = (const int*)d_in[2];
  const float* degree = (const float*)d_in[3];
  const float* sn_g   = (const float*)d_in[4];
  const float* sn_b   = (const float*)d_in[5];
  const float* nn_g   = (const float*)d_in[6];
  const float* nn_b   = (const float*)d_in[7];
  const float* W1     = (const float*)d_in[8];
  const float* b1     = (const float*)d_in[9];
  const float* W2     = (const float*)d_in[10];
  const float* b2     = (const float*)d_in[11];

  char* ws = (char*)d_ws;
  const size_t H_BYTES = (size_t)TOK * 256 * 2;          // 51.2 MB
  unsigned short* h = (unsigned short*)ws;               // [TOK][256] bf16
  // scratch region (within the second 51.2 MB window, before W1t):
  char* csr = ws + H_BYTES;
  int* cnt           = (int*)(csr);                       // 50000 ints (memset 0)
  unsigned short* xb = (unsigned short*)(csr + 4194304);  // [N][2][128] bf16, 25.6 MB
  int* bucket        = (int*)(csr + 33554432);            // [N][CAP] ints, 12.8 MB
  unsigned short* W1t = (unsigned short*)(ws + 2 * H_BYTES);
  unsigned short* W2t = W1t + 65536;

  hipMemsetAsync(cnt, 0, (size_t)N_ * sizeof(int), stream);
  fill_k<<<(E_ / 4 + 255) / 256, 256, 0, stream>>>(esrc, edst, cnt, bucket);
  prep_k<<<3221, 1024, 0, stream>>>(x, W1, W2, xb, W1t, W2t);
  gather_ln_k<<<N_ / 4, 256, 0, stream>>>(xb, degree, bucket,
                                          sn_g, sn_b, nn_g, nn_b, h);
  fused_mlp_k<<<(TOK + 63) / 64, 256, 0, stream>>>(h, W1t, W2t, b1, b2,
                                                   x, (float*)d_out, TOK);
}

// Round 17
// 271.371 us; speedup vs baseline: 2.3885x; 1.0793x over previous
//
#include <hip/hip_runtime.h>
#include <cstdint>

#define B_ 2
#define N_ 50000
#define D_ 128
#define E_ 800000
#define TOK 100000   // B_*N_
#define CAP 64       // bucket capacity; deg ~ Poisson(16), P(>=64) ~ 2e-18

typedef __bf16 bf16x8 __attribute__((ext_vector_type(8)));
typedef float f32x4 __attribute__((ext_vector_type(4)));

__device__ __forceinline__ unsigned short f2bf(float f) {
  union { float f; uint32_t u; } v; v.f = f;
  uint32_t u = v.u;
  return (unsigned short)((u + 0x7FFFu + ((u >> 16) & 1u)) >> 16);
}
__device__ __forceinline__ float uasf(uint32_t u) {
  union { uint32_t u; float f; } v; v.u = u; return v.f;
}
// tanh-form GELU: v * sigmoid(1.5958*(v + 0.044715 v^3)); max |err| vs exact
// erf-GELU ~3e-4 << bf16 rounding of h1. Branch-free saturation.
__device__ __forceinline__ float fast_gelu(float v) {
  float p = v * (1.5957691f + 0.07135481f * v * v);
  return v * __builtin_amdgcn_rcpf(1.0f + __expf(-p));
}

// ==== merged prep+fill (independent work, no sync; one dispatch) ============
// Blocks 0..195: bucket-CSR fill (4096 edges/block) -- latency/random-
//   writeback bound (round-16: 0.2% VALU, 10% HBM), scheduled FIRST so its
//   idle shadow absorbs the streaming work below.
// Blocks 196..3320: x -> batch-interleaved bf16 xb[node][2][128].
// Blocks 3321..3416: W transpose -> fragment-major bf16 (16(n)x32(k) tiles,
//   element (n,k) at lane=(n&15)+16*((k>>3)&3), j=k&7 -> wave b-frag load =
//   base + lane*16B, one coalesced 1KB transaction).
// No scan anywhere: fixed-capacity buckets + input `degree` give gather its
// row bounds directly (r0 = node*CAP, r1 = r0 + deg).
__global__ __launch_bounds__(1024) void prepfill_k(
    const float* __restrict__ x, const float* __restrict__ W1,
    const float* __restrict__ W2,
    const int* __restrict__ esrc, const int* __restrict__ edst,
    unsigned short* __restrict__ xb, unsigned short* __restrict__ W1t,
    unsigned short* __restrict__ W2t,
    int* __restrict__ cnt, int* __restrict__ bucket) {
  const int blk = blockIdx.x;
  if (blk < 196) {                 // bucket-CSR fill, 4 edges/thread
    int e4 = (blk * 1024 + threadIdx.x) * 4;
    if (e4 < E_) {
      int4 s4 = *(const int4*)(esrc + e4);
      int4 d4 = *(const int4*)(edst + e4);
      int p0 = atomicAdd(&cnt[d4.x], 1); bucket[d4.x * CAP + p0] = s4.x;
      int p1 = atomicAdd(&cnt[d4.y], 1); bucket[d4.y * CAP + p1] = s4.y;
      int p2 = atomicAdd(&cnt[d4.z], 1); bucket[d4.z * CAP + p2] = s4.z;
      int p3 = atomicAdd(&cnt[d4.w], 1); bucket[d4.w * CAP + p3] = s4.w;
    }
  } else if (blk < 3321) {         // x -> xb (bf16, batch-interleaved)
    int q = ((blk - 196) * 1024 + threadIdx.x) * 4;
    int node = q >> 8;
    int rem = q & 255;
    int b = rem >> 7, c = rem & 127;
    float4 v = *(const float4*)(x + (size_t)b * (N_ * D_) + node * 128 + c);
    uint2 p = { (uint32_t)f2bf(v.x) | ((uint32_t)f2bf(v.y) << 16),
                (uint32_t)f2bf(v.z) | ((uint32_t)f2bf(v.w) << 16) };
    *(uint2*)(xb + q) = p;
  } else {                         // weight transpose -> fragment-major bf16
    int t = (blk - 3321) * 1024 + threadIdx.x;
    if (t < 65536) {
      int n = t >> 8, k = t & 255;
      int f = (n >> 4) * 8 + (k >> 5);
      int pos = ((n & 15) + ((k >> 3) & 3) * 16) * 8 + (k & 7);
      W1t[f * 512 + pos] = f2bf(W1[k * 256 + n]);
    } else {
      int t2 = t - 65536;
      int n = t2 >> 8, k = t2 & 255;
      int f = (n >> 4) * 8 + (k >> 5);
      int pos = ((n & 15) + ((k >> 3) & 3) * 16) * 8 + (k & 7);
      W2t[f * 512 + pos] = f2bf(W2[k * 128 + n]);
    }
  }
}

// ---------------- fused gather + dual LayerNorm -> h = [LN(x), LN(nb)] -----
// One wave per node. 32 lanes cover the full 512B row (uint4/lane), the two
// 32-lane halves (g=0/1) process 2 edges in parallel -> 8x16B loads in flight
// per lane. Row bounds from degree (input): r0 = node*CAP, r1 = r0 + deg.
__global__ __launch_bounds__(256) void gather_ln_k(
    const unsigned short* __restrict__ xb,
    const float* __restrict__ degree, const int* __restrict__ ss,
    const float* __restrict__ sn_g, const float* __restrict__ sn_b,
    const float* __restrict__ nn_g, const float* __restrict__ nn_b,
    unsigned short* __restrict__ h) {
  const int node = blockIdx.x * 4 + (threadIdx.x >> 6);
  const int lane = threadIdx.x & 63;
  const int g = lane >> 5;          // edge-parallel subgroup
  const int l32 = lane & 31;        // 16B chunk within the 512B row
  const int deg = (int)(degree[node] + 0.5f);
  const int r0 = node * CAP, r1 = r0 + deg;
  const unsigned short* xrow = xb + l32 * 8;   // 8 bf16 per lane
  float acc[8] = {0.f, 0.f, 0.f, 0.f, 0.f, 0.f, 0.f, 0.f};
  for (int e = r0; e < r1; e += 16) {
    int idx[8];
#pragma unroll
    for (int j = 0; j < 8; ++j) {
      int ej = e + 2 * j + g;
      idx[j] = ss[(ej < r1) ? ej : r0];
    }
    uint4 v[8];
#pragma unroll
    for (int j = 0; j < 8; ++j)
      v[j] = *(const uint4*)(xrow + (size_t)idx[j] * 256);
#pragma unroll
    for (int j = 0; j < 8; ++j) {
      if (e + 2 * j + g < r1) {
        acc[0] += uasf(v[j].x << 16); acc[1] += uasf(v[j].x & 0xffff0000u);
        acc[2] += uasf(v[j].y << 16); acc[3] += uasf(v[j].y & 0xffff0000u);
        acc[4] += uasf(v[j].z << 16); acc[5] += uasf(v[j].z & 0xffff0000u);
        acc[6] += uasf(v[j].w << 16); acc[7] += uasf(v[j].w & 0xffff0000u);
      }
    }
  }
  // combine the two edge-parallel halves
#pragma unroll
  for (int k = 0; k < 8; ++k) acc[k] += __shfl_xor(acc[k], 32);
  const float invd = 1.0f / fmaxf((float)deg, 1.0f);
  float nb[8];
#pragma unroll
  for (int k = 0; k < 8; ++k) nb[k] = acc[k] * invd;
  uint4 xq = *(const uint4*)(xrow + (size_t)node * 256);  // own row (bf16)
  float xv[8];
  xv[0] = uasf(xq.x << 16); xv[1] = uasf(xq.x & 0xffff0000u);
  xv[2] = uasf(xq.y << 16); xv[3] = uasf(xq.y & 0xffff0000u);
  xv[4] = uasf(xq.z << 16); xv[5] = uasf(xq.z & 0xffff0000u);
  xv[6] = uasf(xq.w << 16); xv[7] = uasf(xq.w & 0xffff0000u);
  float sx = 0.f, sxx = 0.f, sn = 0.f, snn = 0.f;
#pragma unroll
  for (int k = 0; k < 8; ++k) {
    sx += xv[k]; sxx += xv[k] * xv[k];
    sn += nb[k]; snn += nb[k] * nb[k];
  }
  // reduce within the 16-lane batch group (lanes [0,16) b0, [16,32) b1, etc.)
#pragma unroll
  for (int off = 1; off < 16; off <<= 1) {
    sx  += __shfl_xor(sx, off);  sxx += __shfl_xor(sxx, off);
    sn  += __shfl_xor(sn, off);  snn += __shfl_xor(snn, off);
  }
  const float r = 1.0f / 128.0f;
  float mx = sx * r, vx = fmaxf(sxx * r - mx * mx, 0.f);
  float mn = sn * r, vn = fmaxf(snn * r - mn * mn, 0.f);
  float rx = rsqrtf(vx + 1e-5f), rn = rsqrtf(vn + 1e-5f);
  const int c = (l32 & 15) * 8;
  // g==0 lanes write y = LN(x); g==1 lanes write z = LN(nb)
  const float* gp = g ? nn_g : sn_g;
  const float* bp = g ? nn_b : sn_b;
  float4 g0 = *(const float4*)(gp + c), g1 = *(const float4*)(gp + c + 4);
  float4 b0 = *(const float4*)(bp + c), b1v = *(const float4*)(bp + c + 4);
  float gw[8] = {g0.x, g0.y, g0.z, g0.w, g1.x, g1.y, g1.z, g1.w};
  float bw[8] = {b0.x, b0.y, b0.z, b0.w, b1v.x, b1v.y, b1v.z, b1v.w};
  float mu = g ? mn : mx;
  float rs_ = g ? rn : rx;
  float o[8];
#pragma unroll
  for (int k = 0; k < 8; ++k) {
    float s = g ? nb[k] : xv[k];
    o[k] = (s - mu) * rs_ * gw[k] + bw[k];
  }
  uint4 po;
  po.x = (uint32_t)f2bf(o[0]) | ((uint32_t)f2bf(o[1]) << 16);
  po.y = (uint32_t)f2bf(o[2]) | ((uint32_t)f2bf(o[3]) << 16);
  po.z = (uint32_t)f2bf(o[4]) | ((uint32_t)f2bf(o[5]) << 16);
  po.w = (uint32_t)f2bf(o[6]) | ((uint32_t)f2bf(o[7]) << 16);
  unsigned short* hr = h + ((size_t)(l32 >> 4) * N_ + node) * 256 + g * 128 + c;
  *(uint4*)hr = po;
}

// ---------------- fused MLP: out = GELU(h @ W1^T + b1) @ W2^T + b2 + x ------
// v7 (round-12 best, kept): BM=64, As 32KB + Hc 8KB = 40KB -> 4 blocks/CU,
// 16 waves/CU. BM=32 (32 waves/CU) regressed: 2x blocks doubled W/L2 traffic
// and halved MFMA:load mix. BM=128 (2 blocks/CU) regressed: TLP-starved.
__global__ __launch_bounds__(256, 4) void fused_mlp_k(
    const unsigned short* __restrict__ A,      // h [M][256] bf16
    const unsigned short* __restrict__ W1t,    // frag-major [16x8 tiles][512]
    const unsigned short* __restrict__ W2t,    // frag-major [8x8 tiles][512]
    const float* __restrict__ b1,
    const float* __restrict__ b2,
    const float* __restrict__ resid,           // x fp32 [M][128]
    float* __restrict__ outp, int M) {
  __shared__ unsigned short As[64 * 256];    // 32768 B, swizzled: chunk ^ (row&7)
  __shared__ unsigned short Hc[64 * 64];     // 8192 B, swizzled: elem ^ ((row&7)<<3)
  const int tid = threadIdx.x;
  const int wave = tid >> 6, lane = tid & 63;
  const int wr = wave >> 1;        // 0..1: 32-row strip
  const int wc = wave & 1;         // 0/1: column half
  const int quad = lane >> 4, l15 = lane & 15;
  const int m0 = blockIdx.x * 64;
  // ---- stage A tile once: 64 rows x 32 16B-chunks, 8 iters x 256 thr ----
  {
    uint4 v[8];
#pragma unroll
    for (int it = 0; it < 8; ++it) {
      int id = it * 256 + tid;
      int r = id >> 5, c16 = id & 31;
      int gm = m0 + r;
      uint4 va = {0u, 0u, 0u, 0u};
      if (gm < M) va = *(const uint4*)(A + (size_t)gm * 256 + c16 * 8);
      v[it] = va;
    }
#pragma unroll
    for (int it = 0; it < 8; ++it) {
      int id = it * 256 + tid;
      int r = id >> 5, c16 = id & 31;
      *(uint4*)(&As[r * 256 + (c16 ^ (r & 7)) * 8]) = v[it];
    }
  }
  f32x4 acc2[2][4] = {};
  __syncthreads();
  for (int nc = 0; nc < 4; ++nc) {
    // ---- gemm1 chunk: 64 rows x 64 h1-cols; wave owns 32x32 ----
    f32x4 acc1[2][2] = {};
#pragma unroll
    for (int kc = 0; kc < 256; kc += 32) {
      bf16x8 a[2], b[2];
#pragma unroll
      for (int i = 0; i < 2; ++i) {
        int row = wr * 32 + i * 16 + l15;
        a[i] = *(const bf16x8*)(&As[row * 256 + ((kc + quad * 8) ^ ((row & 7) << 3))]);
      }
#pragma unroll
      for (int i = 0; i < 2; ++i) {
        int ftile = (nc * 4 + wc * 2 + i) * 8 + (kc >> 5);
        b[i] = *(const bf16x8*)(W1t + ftile * 512 + lane * 8);
      }
#pragma unroll
      for (int mi = 0; mi < 2; ++mi)
#pragma unroll
        for (int ni = 0; ni < 2; ++ni)
          acc1[mi][ni] = __builtin_amdgcn_mfma_f32_16x16x32_bf16(a[mi], b[ni], acc1[mi][ni], 0, 0, 0);
    }
    __syncthreads();   // prev iter's gemm2 finished reading Hc
    // ---- GELU(acc1 + b1) -> Hc (bf16, swizzled) ----
#pragma unroll
    for (int mi = 0; mi < 2; ++mi)
#pragma unroll
      for (int ni = 0; ni < 2; ++ni) {
        int col = wc * 32 + ni * 16 + l15;
        float bv = b1[nc * 64 + col];
#pragma unroll
        for (int rr = 0; rr < 4; ++rr) {
          int row = wr * 32 + mi * 16 + quad * 4 + rr;
          Hc[row * 64 + (col ^ ((row & 7) << 3))] = f2bf(fast_gelu(acc1[mi][ni][rr] + bv));
        }
      }
    __syncthreads();
    // ---- gemm2 partial: acc2 += Hc(64x64) @ W2[:, nc*64 .. +64]; 32x64/wave
#pragma unroll
    for (int kc = 0; kc < 64; kc += 32) {
      bf16x8 a[2], b[4];
#pragma unroll
      for (int i = 0; i < 2; ++i) {
        int row = wr * 32 + i * 16 + l15;
        a[i] = *(const bf16x8*)(&Hc[row * 64 + ((kc + quad * 8) ^ ((row & 7) << 3))]);
      }
#pragma unroll
      for (int i = 0; i < 4; ++i) {
        int ftile = (wc * 4 + i) * 8 + nc * 2 + (kc >> 5);
        b[i] = *(const bf16x8*)(W2t + ftile * 512 + lane * 8);
      }
#pragma unroll
      for (int mi = 0; mi < 2; ++mi)
#pragma unroll
        for (int ni = 0; ni < 4; ++ni)
          acc2[mi][ni] = __builtin_amdgcn_mfma_f32_16x16x32_bf16(a[mi], b[ni], acc2[mi][ni], 0, 0, 0);
    }
  }
  // ---- epilogue: + b2 + resid, fp32 out ----
#pragma unroll
  for (int mi = 0; mi < 2; ++mi)
#pragma unroll
    for (int ni = 0; ni < 4; ++ni) {
      int col = wc * 64 + ni * 16 + l15;
      float bv = b2[col];
#pragma unroll
      for (int rr = 0; rr < 4; ++rr) {
        int row = m0 + wr * 32 + mi * 16 + quad * 4 + rr;
        if (row < M) {
          float v = acc2[mi][ni][rr] + bv + resid[(size_t)row * 128 + col];
          outp[(size_t)row * 128 + col] = v;
        }
      }
    }
}

extern "C" void kernel_launch(void* const* d_in, const int* in_sizes, int n_in,
                              void* d_out, int out_size, void* d_ws, size_t ws_size,
                              hipStream_t stream) {
  const float* x      = (const float*)d_in[0];
  const int* esrc     = (const int*)d_in[1];
  const int* edst     = (const int*)d_in[2];
  const float* degree = (const float*)d_in[3];
  const float* sn_g   = (const float*)d_in[4];
  const float* sn_b   = (const float*)d_in[5];
  const float* nn_g   = (const float*)d_in[6];
  const float* nn_b   = (const float*)d_in[7];
  const float* W1     = (const float*)d_in[8];
  const float* b1     = (const float*)d_in[9];
  const float* W2     = (const float*)d_in[10];
  const float* b2     = (const float*)d_in[11];

  char* ws = (char*)d_ws;
  const size_t H_BYTES = (size_t)TOK * 256 * 2;          // 51.2 MB
  unsigned short* h = (unsigned short*)ws;               // [TOK][256] bf16
  // scratch region (within the second 51.2 MB window, before W1t):
  char* csr = ws + H_BYTES;
  int* cnt           = (int*)(csr);                       // 50000 ints (memset 0)
  unsigned short* xb = (unsigned short*)(csr + 4194304);  // [N][2][128] bf16, 25.6 MB
  int* bucket        = (int*)(csr + 33554432);            // [N][CAP] ints, 12.8 MB
  unsigned short* W1t = (unsigned short*)(ws + 2 * H_BYTES);
  unsigned short* W2t = W1t + 65536;

  hipMemsetAsync(cnt, 0, (size_t)N_ * sizeof(int), stream);
  prepfill_k<<<3417, 1024, 0, stream>>>(x, W1, W2, esrc, edst,
                                        xb, W1t, W2t, cnt, bucket);
  gather_ln_k<<<N_ / 4, 256, 0, stream>>>(xb, degree, bucket,
                                          sn_g, sn_b, nn_g, nn_b, h);
  fused_mlp_k<<<(TOK + 63) / 64, 256, 0, stream>>>(h, W1t, W2t, b1, b2,
                                                   x, (float*)d_out, TOK);
}